// Round 1
// baseline (359.970 us; speedup 1.0000x reference)
//
#include <hip/hip_runtime.h>
#include <hip/hip_bf16.h>

// GAS(1,1) Gaussian-copula log-likelihood scan, T = 2^20.
// Strategy: nonlinear recurrence, but contractive (B~0.9526 for f, alpha=0.99
// for s_var). Chunk the series; each chunk warms up for WARM steps from a
// guessed state; 0.99^1536 ~ 2e-7 residual error vs ~2% tolerance.

#define T_LEN   (1 << 20)
#define CHUNK_LEN 16
#define NCHUNK  (T_LEN / CHUNK_LEN)   // 65536 chunks -> 1024 waves -> 1/SIMD
#define WARM    1536

// ---------------- ndtri via Giles' single-precision erfinv ----------------
__device__ __forceinline__ float ndtri_fast(float u) {
    // ndtri(u) = sqrt(2) * erfinv(2u - 1);  w = -log((1-t)(1+t)) = -log(4u(1-u))
    float t = 2.0f * u - 1.0f;
    float w = -__logf(fmaxf(4.0f * u * (1.0f - u), 1e-38f));
    float p;
    if (w < 5.0f) {
        w = w - 2.5f;
        p =            2.81022636e-08f;
        p = fmaf(p, w, 3.43273939e-07f);
        p = fmaf(p, w, -3.5233877e-06f);
        p = fmaf(p, w, -4.39150654e-06f);
        p = fmaf(p, w, 0.00021858087f);
        p = fmaf(p, w, -0.00125372503f);
        p = fmaf(p, w, -0.00417768164f);
        p = fmaf(p, w, 0.246640727f);
        p = fmaf(p, w, 1.50140941f);
    } else {
        w = __builtin_amdgcn_sqrtf(w) - 3.0f;
        p =            -0.000200214257f;
        p = fmaf(p, w, 0.000100950558f);
        p = fmaf(p, w, 0.00134934322f);
        p = fmaf(p, w, -0.00367342844f);
        p = fmaf(p, w, 0.00573950773f);
        p = fmaf(p, w, -0.0076224613f);
        p = fmaf(p, w, 0.00943887047f);
        p = fmaf(p, w, 1.00167406f);
        p = fmaf(p, w, 2.83297682f);
    }
    return 1.41421356237f * p * t;
}

// ---------------- kernel 1: precompute (x^2+y^2, -2xy) per t ----------------
__global__ void prep_kernel(const float* __restrict__ u,
                            const float* __restrict__ v,
                            float2* __restrict__ sp) {
    int i = blockIdx.x * blockDim.x + threadIdx.x;
    if (i >= T_LEN) return;
    float uu = fminf(fmaxf(u[i], 1e-9f), 1.0f - 1e-9f);
    float vv = fminf(fmaxf(v[i], 1e-9f), 1.0f - 1e-9f);
    float x = ndtri_fast(uu);
    float y = ndtri_fast(vv);
    sp[i] = make_float2(fmaf(x, x, y * y), -2.0f * x * y);
}

// ---------------- kernel 2: chunked warm-up scan ----------------
__launch_bounds__(256, 1)
__global__ void scan_kernel(const float2* __restrict__ sp,
                            const float* __restrict__ p_omega,
                            const float* __restrict__ p_A,
                            const float* __restrict__ p_Blogit,
                            float* __restrict__ out) {
    const int c = blockIdx.x * blockDim.x + threadIdx.x;   // chunk id
    const float omega = p_omega[0];
    const float A     = p_A[0];
    const float B     = 1.0f / (1.0f + __expf(-p_Blogit[0]));  // sigmoid

    const int t0 = c * CHUNK_LEN - WARM;
    float f   = omega;   // guessed (and, for early chunks, exact) init
    float s   = 1.0f;
    float acc = 0.0f;

    for (int i = 0; i < WARM + CHUNK_LEN; ++i) {
        int  t    = t0 + i;
        bool live = (t >= 0);           // dead steps: keep state == true init
        float2 d  = sp[live ? t : 0];
        float sq  = d.x;
        float m2p = d.y;                // -2*x*y

        // rho = 0.999*tanh(f); tanh via exp: th = 1 - 2/(e^{2f}+1)
        float E    = __expf(2.0f * f);
        float r    = __builtin_amdgcn_rcpf(E + 1.0f);
        float th   = fmaf(-2.0f, r, 1.0f);
        float rho  = 0.999f * th;
        float D    = fmaf(-rho, rho, 1.0f) + 1e-8f;
        float invD = __builtin_amdgcn_rcpf(D);
        float z    = fmaf(rho, m2p, sq);     // sq - 2*rho*x*y
        float zi   = z * invD;

        if (i >= WARM) {                     // wave-uniform: no divergence
            float ll = fmaf(-0.5f, __logf(D), -0.5f * (zi - sq));
            acc += ll;
        }

        // score = (rho/D + xy/D - rho*z/D^2) * 0.999*(1-th^2)
        float pxy    = -0.5f * m2p;          // x*y
        float dll    = (rho + pxy - rho * zi) * invD;
        float score  = dll * (fmaf(-th, th, 1.0f) * 0.999f);
        float snew   = fmaf(0.99f, s, 0.01f * score * score);
        float scaled = score * __builtin_amdgcn_rsqf(snew + 1e-8f);
        float fnew   = fmaf(B, f - omega, fmaf(A, scaled, omega));

        f = live ? fnew : f;
        s = live ? snew : s;
    }

    // block reduction -> one atomicAdd per block
    __shared__ float red[256];
    red[threadIdx.x] = acc;
    __syncthreads();
    for (int off = 128; off > 0; off >>= 1) {
        if (threadIdx.x < off) red[threadIdx.x] += red[threadIdx.x + off];
        __syncthreads();
    }
    if (threadIdx.x == 0) atomicAdd(out, red[0]);
}

extern "C" void kernel_launch(void* const* d_in, const int* in_sizes, int n_in,
                              void* d_out, int out_size, void* d_ws, size_t ws_size,
                              hipStream_t stream) {
    const float* u       = (const float*)d_in[0];
    const float* v       = (const float*)d_in[1];
    const float* omega   = (const float*)d_in[2];
    const float* A       = (const float*)d_in[3];
    const float* B_logit = (const float*)d_in[4];
    float*       out     = (float*)d_out;
    float2*      sp      = (float2*)d_ws;          // 8 MiB: (x^2+y^2, -2xy)

    prep_kernel<<<T_LEN / 256, 256, 0, stream>>>(u, v, sp);
    hipMemsetAsync(d_out, 0, sizeof(float), stream);
    scan_kernel<<<NCHUNK / 256, 256, 0, stream>>>(sp, omega, A, B_logit, out);
}

// Round 2
// 166.479 us; speedup vs baseline: 2.1623x; 2.1623x over previous
//
#include <hip/hip_runtime.h>
#include <hip/hip_bf16.h>

// GAS(1,1) Gaussian-copula log-likelihood scan, T = 2^20.
// Chunked warm-up scan: recurrence is contractive (B~0.9526 on f, 0.99 on
// s_var). W=768: residual state error ~0.99^768=4.4e-4; measured error at
// W=1536 was ~0 => huge margin vs threshold 142.
//
// R2 changes vs R1 (312us scan):
//  - W 1536 -> 768 (absmax evidence: error K*0.99^W with K <= ~5e4)
//  - group-of-4 steps, float4-pair loads prefetching the NEXT group:
//    hides ~200cy L2 latency behind ~4 chain-steps of ALU (R1 had VGPR=12,
//    no prefetch, ~480 cy/step incl. vmcnt(0) stall every step)
//  - no per-step dead-step cndmasks: clamp tstart/nsteps instead (early
//    chunks are exact from the true init; counts stay multiples of 4)
//  - shorter chain: rho = 0.999-1.998r, 0.999*(1-th^2) = 3.996*r*(1-r)
//    where r = rcp(e^{2f}+1)

#define T_LEN     (1 << 20)
#define CHUNK_LEN 16
#define NCHUNK    (T_LEN / CHUNK_LEN)   // 65536 threads -> 1024 waves -> 1/SIMD
#define WARM      768                   // multiple of 16 (keeps loads aligned)

// ---------------- ndtri via Giles' single-precision erfinv ----------------
__device__ __forceinline__ float ndtri_fast(float u) {
    float t = 2.0f * u - 1.0f;
    float w = -__logf(fmaxf(4.0f * u * (1.0f - u), 1e-38f));
    float p;
    if (w < 5.0f) {
        w = w - 2.5f;
        p =            2.81022636e-08f;
        p = fmaf(p, w, 3.43273939e-07f);
        p = fmaf(p, w, -3.5233877e-06f);
        p = fmaf(p, w, -4.39150654e-06f);
        p = fmaf(p, w, 0.00021858087f);
        p = fmaf(p, w, -0.00125372503f);
        p = fmaf(p, w, -0.00417768164f);
        p = fmaf(p, w, 0.246640727f);
        p = fmaf(p, w, 1.50140941f);
    } else {
        w = __builtin_amdgcn_sqrtf(w) - 3.0f;
        p =            -0.000200214257f;
        p = fmaf(p, w, 0.000100950558f);
        p = fmaf(p, w, 0.00134934322f);
        p = fmaf(p, w, -0.00367342844f);
        p = fmaf(p, w, 0.00573950773f);
        p = fmaf(p, w, -0.0076224613f);
        p = fmaf(p, w, 0.00943887047f);
        p = fmaf(p, w, 1.00167406f);
        p = fmaf(p, w, 2.83297682f);
    }
    return 1.41421356237f * p * t;
}

// ---------------- kernel 1: precompute (x^2+y^2, -2xy), 4 elems/thread ----
__global__ void prep_kernel(const float4* __restrict__ u4,
                            const float4* __restrict__ v4,
                            float4* __restrict__ sp4) {
    int i = blockIdx.x * blockDim.x + threadIdx.x;   // i < T_LEN/4
    float4 uu = u4[i];
    float4 vv = v4[i];
    float x0 = ndtri_fast(fminf(fmaxf(uu.x, 1e-9f), 1.0f - 1e-9f));
    float x1 = ndtri_fast(fminf(fmaxf(uu.y, 1e-9f), 1.0f - 1e-9f));
    float x2 = ndtri_fast(fminf(fmaxf(uu.z, 1e-9f), 1.0f - 1e-9f));
    float x3 = ndtri_fast(fminf(fmaxf(uu.w, 1e-9f), 1.0f - 1e-9f));
    float y0 = ndtri_fast(fminf(fmaxf(vv.x, 1e-9f), 1.0f - 1e-9f));
    float y1 = ndtri_fast(fminf(fmaxf(vv.y, 1e-9f), 1.0f - 1e-9f));
    float y2 = ndtri_fast(fminf(fmaxf(vv.z, 1e-9f), 1.0f - 1e-9f));
    float y3 = ndtri_fast(fminf(fmaxf(vv.w, 1e-9f), 1.0f - 1e-9f));
    float4 o0, o1;
    o0.x = fmaf(x0, x0, y0 * y0);  o0.y = -2.0f * x0 * y0;
    o0.z = fmaf(x1, x1, y1 * y1);  o0.w = -2.0f * x1 * y1;
    o1.x = fmaf(x2, x2, y2 * y2);  o1.y = -2.0f * x2 * y2;
    o1.z = fmaf(x3, x3, y3 * y3);  o1.w = -2.0f * x3 * y3;
    sp4[2 * i]     = o0;
    sp4[2 * i + 1] = o1;
}

// ---------------- one GAS step; returns ll ----------------
__device__ __forceinline__ float gas_step(float sq, float m2p,
                                          float& f, float& s,
                                          float omega, float A, float B) {
    float E    = __expf(2.0f * f);                    // e^{2f}
    float r    = __builtin_amdgcn_rcpf(E + 1.0f);     // 1/(e^{2f}+1)
    float rho  = fmaf(-1.998f, r, 0.999f);            // 0.999*tanh(f)
    float gg   = 3.996f * r * (1.0f - r);             // 0.999*(1-th^2)
    float D    = fmaf(-rho, rho, 1.0f) + 1e-8f;
    float invD = __builtin_amdgcn_rcpf(D);
    float z    = fmaf(rho, m2p, sq);                  // sq - 2 rho x y
    float zi   = z * invD;
    float ll   = fmaf(-0.5f, __logf(D), 0.5f * (sq - zi));
    float pxy  = -0.5f * m2p;                         // x*y
    float dll  = fmaf(-rho, zi, rho + pxy) * invD;
    float score  = dll * gg;
    float snew   = fmaf(0.99f, s, 0.01f * (score * score));
    float scaled = score * __builtin_amdgcn_rsqf(snew + 1e-8f);
    f = fmaf(A, scaled, fmaf(B, f - omega, omega));
    s = snew;
    return ll;
}

// ---------------- kernel 2: chunked warm-up scan, 4-step groups ----------
__launch_bounds__(256, 1)
__global__ void scan_kernel(const float2* __restrict__ sp,
                            const float* __restrict__ p_omega,
                            const float* __restrict__ p_A,
                            const float* __restrict__ p_Blogit,
                            float* __restrict__ out) {
    const int c = blockIdx.x * blockDim.x + threadIdx.x;   // chunk id
    const float omega = p_omega[0];
    const float A     = p_A[0];
    const float B     = 1.0f / (1.0f + __expf(-p_Blogit[0]));

    const int t0     = c * CHUNK_LEN - WARM;
    const int tstart = (t0 < 0) ? 0 : t0;            // early chunks: exact init
    const int nsteps = (t0 < 0) ? (t0 + WARM + CHUNK_LEN) : (WARM + CHUNK_LEN);
    const int G      = nsteps >> 2;                  // groups of 4 (nsteps%4==0)
    const int GL     = G - 4;                        // last 16 steps are live

    const float4* __restrict__ pf = (const float4*)(sp + tstart);  // 16B aligned

    float f = omega, s = 1.0f, acc = 0.0f;
    float4 a = pf[0], b = pf[1];
    for (int g = 0; g < G; ++g) {
        int gn = (g + 1 < G) ? (g + 1) : g;          // clamp: no OOB prefetch
        float4 na = pf[2 * gn];
        float4 nb = pf[2 * gn + 1];
        float ll0 = gas_step(a.x, a.y, f, s, omega, A, B);
        float ll1 = gas_step(a.z, a.w, f, s, omega, A, B);
        float ll2 = gas_step(b.x, b.y, f, s, omega, A, B);
        float ll3 = gas_step(b.z, b.w, f, s, omega, A, B);
        if (g >= GL) acc += (ll0 + ll1) + (ll2 + ll3);
        a = na; b = nb;
    }

    // block reduction -> one atomicAdd per block
    __shared__ float red[256];
    red[threadIdx.x] = acc;
    __syncthreads();
    for (int off = 128; off > 0; off >>= 1) {
        if (threadIdx.x < off) red[threadIdx.x] += red[threadIdx.x + off];
        __syncthreads();
    }
    if (threadIdx.x == 0) atomicAdd(out, red[0]);
}

extern "C" void kernel_launch(void* const* d_in, const int* in_sizes, int n_in,
                              void* d_out, int out_size, void* d_ws, size_t ws_size,
                              hipStream_t stream) {
    const float* u       = (const float*)d_in[0];
    const float* v       = (const float*)d_in[1];
    const float* omega   = (const float*)d_in[2];
    const float* A       = (const float*)d_in[3];
    const float* B_logit = (const float*)d_in[4];
    float*       out     = (float*)d_out;
    float2*      sp      = (float2*)d_ws;            // 8 MiB: (x^2+y^2, -2xy)

    prep_kernel<<<T_LEN / 4 / 256, 256, 0, stream>>>(
        (const float4*)u, (const float4*)v, (float4*)sp);
    hipMemsetAsync(d_out, 0, sizeof(float), stream);
    scan_kernel<<<NCHUNK / 256, 256, 0, stream>>>(sp, omega, A, B_logit, out);
}

// Round 3
// 97.359 us; speedup vs baseline: 3.6974x; 1.7100x over previous
//
#include <hip/hip_runtime.h>
#include <hip/hip_bf16.h>

// GAS(1,1) Gaussian-copula log-likelihood scan, T = 2^20.
// Chunked warm-up scan: recurrence is contractive (B~0.9526 on f, 0.99 on
// s_var). Error model (calibrated on W=768/1536 runs, both absmax 0.0):
// total_err ~ 150 * 0.99^W random-sign + small bias; W=256 -> ~1-20 << 142.
//
// R3 changes vs R2 (scan 105us, total 166us):
//  - WARM 768 -> 256 (272 steps/thread vs 784)
//  - warm/live loop split: no v_log_f32 / ll math in 256 warm steps
//  - live 16-step tile (8x float4) preloaded BEFORE warm loop (latency free)
//  - memset dispatch dropped: prep zeroes out[0] (3 -> 2 dispatches;
//    ~50us of the R2 total was non-scan overhead)
//  - D = fma(-rho,rho,1.0) without +1e-8 (below ulp effect on result)

#define T_LEN     (1 << 20)
#define CHUNK_LEN 16
#define NCHUNK    (T_LEN / CHUNK_LEN)   // 65536 threads -> 1024 waves -> 1/SIMD
#define WARM      256                   // multiple of 16

// ---------------- ndtri via Giles' single-precision erfinv ----------------
__device__ __forceinline__ float ndtri_fast(float u) {
    float t = 2.0f * u - 1.0f;
    float w = -__logf(fmaxf(4.0f * u * (1.0f - u), 1e-38f));
    float p;
    if (w < 5.0f) {
        w = w - 2.5f;
        p =            2.81022636e-08f;
        p = fmaf(p, w, 3.43273939e-07f);
        p = fmaf(p, w, -3.5233877e-06f);
        p = fmaf(p, w, -4.39150654e-06f);
        p = fmaf(p, w, 0.00021858087f);
        p = fmaf(p, w, -0.00125372503f);
        p = fmaf(p, w, -0.00417768164f);
        p = fmaf(p, w, 0.246640727f);
        p = fmaf(p, w, 1.50140941f);
    } else {
        w = __builtin_amdgcn_sqrtf(w) - 3.0f;
        p =            -0.000200214257f;
        p = fmaf(p, w, 0.000100950558f);
        p = fmaf(p, w, 0.00134934322f);
        p = fmaf(p, w, -0.00367342844f);
        p = fmaf(p, w, 0.00573950773f);
        p = fmaf(p, w, -0.0076224613f);
        p = fmaf(p, w, 0.00943887047f);
        p = fmaf(p, w, 1.00167406f);
        p = fmaf(p, w, 2.83297682f);
    }
    return 1.41421356237f * p * t;
}

// ---------------- kernel 1: precompute (x^2+y^2, -2xy); also zero out ------
__global__ void prep_kernel(const float4* __restrict__ u4,
                            const float4* __restrict__ v4,
                            float4* __restrict__ sp4,
                            float* __restrict__ out) {
    int i = blockIdx.x * blockDim.x + threadIdx.x;   // i < T_LEN/4
    if (i == 0) out[0] = 0.0f;                       // replaces memset dispatch
    float4 uu = u4[i];
    float4 vv = v4[i];
    float x0 = ndtri_fast(fminf(fmaxf(uu.x, 1e-9f), 1.0f - 1e-9f));
    float x1 = ndtri_fast(fminf(fmaxf(uu.y, 1e-9f), 1.0f - 1e-9f));
    float x2 = ndtri_fast(fminf(fmaxf(uu.z, 1e-9f), 1.0f - 1e-9f));
    float x3 = ndtri_fast(fminf(fmaxf(uu.w, 1e-9f), 1.0f - 1e-9f));
    float y0 = ndtri_fast(fminf(fmaxf(vv.x, 1e-9f), 1.0f - 1e-9f));
    float y1 = ndtri_fast(fminf(fmaxf(vv.y, 1e-9f), 1.0f - 1e-9f));
    float y2 = ndtri_fast(fminf(fmaxf(vv.z, 1e-9f), 1.0f - 1e-9f));
    float y3 = ndtri_fast(fminf(fmaxf(vv.w, 1e-9f), 1.0f - 1e-9f));
    float4 o0, o1;
    o0.x = fmaf(x0, x0, y0 * y0);  o0.y = -2.0f * x0 * y0;
    o0.z = fmaf(x1, x1, y1 * y1);  o0.w = -2.0f * x1 * y1;
    o1.x = fmaf(x2, x2, y2 * y2);  o1.y = -2.0f * x2 * y2;
    o1.z = fmaf(x3, x3, y3 * y3);  o1.w = -2.0f * x3 * y3;
    sp4[2 * i]     = o0;
    sp4[2 * i + 1] = o1;
}

// ---------------- one GAS step; LL=true also returns log-density ----------
template <bool LL>
__device__ __forceinline__ float gas_step(float sq, float m2p,
                                          float& f, float& s,
                                          float omega, float A, float B) {
    float E    = __expf(2.0f * f);                    // e^{2f}
    float r    = __builtin_amdgcn_rcpf(E + 1.0f);     // 1/(e^{2f}+1)
    float rho  = fmaf(-1.998f, r, 0.999f);            // 0.999*tanh(f)
    float gg   = 3.996f * r * (1.0f - r);             // 0.999*(1-th^2)
    float D    = fmaf(-rho, rho, 1.0f);               // (+1e-8 below ulp-effect)
    float invD = __builtin_amdgcn_rcpf(D);
    float z    = fmaf(rho, m2p, sq);                  // sq - 2 rho x y
    float zi   = z * invD;
    float ll   = 0.0f;
    if (LL) ll = fmaf(-0.5f, __logf(D), 0.5f * (sq - zi));
    float pxy  = -0.5f * m2p;                         // x*y
    float dll  = fmaf(-rho, zi, rho + pxy) * invD;
    float score  = dll * gg;
    float snew   = fmaf(0.99f, s, 0.01f * (score * score));
    float scaled = score * __builtin_amdgcn_rsqf(snew + 1e-8f);
    f = fmaf(A, scaled, fmaf(B, f - omega, omega));
    s = snew;
    return ll;
}

// ---------------- kernel 2: chunked warm-up scan ---------------------------
__launch_bounds__(256, 1)
__global__ void scan_kernel(const float2* __restrict__ sp,
                            const float* __restrict__ p_omega,
                            const float* __restrict__ p_A,
                            const float* __restrict__ p_Blogit,
                            float* __restrict__ out) {
    const int c = blockIdx.x * blockDim.x + threadIdx.x;   // chunk id
    const float omega = p_omega[0];
    const float A     = p_A[0];
    const float B     = 1.0f / (1.0f + __expf(-p_Blogit[0]));

    const int t0     = c * CHUNK_LEN - WARM;
    const int tstart = (t0 < 0) ? 0 : t0;            // early chunks: exact init
    const int warm   = (t0 < 0) ? (c * CHUNK_LEN) : WARM;   // multiple of 16
    const int Gw     = warm >> 2;                    // warm groups of 4

    const float4* __restrict__ pf = (const float4*)(sp + tstart);  // 16B aligned

    // Preload the full live tile (16 steps = 8 float4) before the warm loop:
    // these loads retire under ~30us of warm compute, so live steps never stall.
    float4 l0 = pf[2 * Gw + 0], l1 = pf[2 * Gw + 1];
    float4 l2 = pf[2 * Gw + 2], l3 = pf[2 * Gw + 3];
    float4 l4 = pf[2 * Gw + 4], l5 = pf[2 * Gw + 5];
    float4 l6 = pf[2 * Gw + 6], l7 = pf[2 * Gw + 7];

    float f = omega, s = 1.0f;

    // ---- warm loop: no ll/log, next-group prefetch ----
    if (Gw > 0) {
        float4 a = pf[0], b = pf[1];
        for (int g = 0; g < Gw; ++g) {
            int gn = (g + 1 < Gw) ? (g + 1) : g;
            float4 na = pf[2 * gn];
            float4 nb = pf[2 * gn + 1];
            gas_step<false>(a.x, a.y, f, s, omega, A, B);
            gas_step<false>(a.z, a.w, f, s, omega, A, B);
            gas_step<false>(b.x, b.y, f, s, omega, A, B);
            gas_step<false>(b.z, b.w, f, s, omega, A, B);
            a = na; b = nb;
        }
    }

    // ---- live loop: 16 steps, fully unrolled from preloaded registers ----
    float acc;
    acc  = gas_step<true>(l0.x, l0.y, f, s, omega, A, B);
    acc += gas_step<true>(l0.z, l0.w, f, s, omega, A, B);
    acc += gas_step<true>(l1.x, l1.y, f, s, omega, A, B);
    acc += gas_step<true>(l1.z, l1.w, f, s, omega, A, B);
    acc += gas_step<true>(l2.x, l2.y, f, s, omega, A, B);
    acc += gas_step<true>(l2.z, l2.w, f, s, omega, A, B);
    acc += gas_step<true>(l3.x, l3.y, f, s, omega, A, B);
    acc += gas_step<true>(l3.z, l3.w, f, s, omega, A, B);
    acc += gas_step<true>(l4.x, l4.y, f, s, omega, A, B);
    acc += gas_step<true>(l4.z, l4.w, f, s, omega, A, B);
    acc += gas_step<true>(l5.x, l5.y, f, s, omega, A, B);
    acc += gas_step<true>(l5.z, l5.w, f, s, omega, A, B);
    acc += gas_step<true>(l6.x, l6.y, f, s, omega, A, B);
    acc += gas_step<true>(l6.z, l6.w, f, s, omega, A, B);
    acc += gas_step<true>(l7.x, l7.y, f, s, omega, A, B);
    acc += gas_step<true>(l7.z, l7.w, f, s, omega, A, B);

    // block reduction -> one atomicAdd per block
    __shared__ float red[256];
    red[threadIdx.x] = acc;
    __syncthreads();
    for (int off = 128; off > 0; off >>= 1) {
        if (threadIdx.x < off) red[threadIdx.x] += red[threadIdx.x + off];
        __syncthreads();
    }
    if (threadIdx.x == 0) atomicAdd(out, red[0]);
}

extern "C" void kernel_launch(void* const* d_in, const int* in_sizes, int n_in,
                              void* d_out, int out_size, void* d_ws, size_t ws_size,
                              hipStream_t stream) {
    const float* u       = (const float*)d_in[0];
    const float* v       = (const float*)d_in[1];
    const float* omega   = (const float*)d_in[2];
    const float* A       = (const float*)d_in[3];
    const float* B_logit = (const float*)d_in[4];
    float*       out     = (float*)d_out;
    float2*      sp      = (float2*)d_ws;            // 8 MiB: (x^2+y^2, -2xy)

    prep_kernel<<<T_LEN / 4 / 256, 256, 0, stream>>>(
        (const float4*)u, (const float4*)v, (float4*)sp, out);
    scan_kernel<<<NCHUNK / 256, 256, 0, stream>>>(sp, omega, A, B_logit, out);
}